// Round 7
// baseline (500.701 us; speedup 1.0000x reference)
//
#include <hip/hip_runtime.h>
#include <hip/hip_bf16.h>

#define H_ 16
#define B_ 8
#define S_ 1024
#define D_ 1024
#define E_ 64
#define HB_ 128
#define LN_EPS 1e-5f

typedef unsigned short u16;
typedef __bf16 bf16x8 __attribute__((ext_vector_type(8)));
typedef u16 u16x8 __attribute__((ext_vector_type(8)));
typedef u16 u16x4 __attribute__((ext_vector_type(4)));
typedef float f32x4 __attribute__((ext_vector_type(4)));

#define MFMA16(a, b, c) __builtin_amdgcn_mfma_f32_16x16x32_bf16( \
    __builtin_bit_cast(bf16x8, (a)), __builtin_bit_cast(bf16x8, (b)), (c), 0, 0, 0)

// async global->LDS, 16B per lane; LDS dest must be wave-uniform base (+lane*16 by HW)
#define GLL16(gp, lp) __builtin_amdgcn_global_load_lds( \
    (const __attribute__((address_space(1))) void*)(gp), \
    (__attribute__((address_space(3))) void*)(lp), 16, 0, 0)

__device__ __forceinline__ u16 f2bf(float x) {
  union { float f; unsigned u; } v; v.f = x;
  unsigned r = v.u + 0x7fffu + ((v.u >> 16) & 1u);
  return (u16)(r >> 16);
}

// ---- prep: all weight transposes in one launch. flat grid 1024 wgs.
__global__ __launch_bounds__(256) void k_transpose_all(
    const float* __restrict__ Wq, const float* __restrict__ Wk,
    const float* __restrict__ Wv, const float* __restrict__ Wp,
    u16* __restrict__ Wt) {
  __shared__ float tile[64][65];
  const int bid = blockIdx.x;
  const int which = bid >> 8, r = bid & 255;
  const float* src;
  int R, C, rt, ct;
  float scale = 1.0f;
  size_t soff, doff;
  if (which < 3) {
    src = which == 0 ? Wq : which == 1 ? Wk : Wv;
    if (which == 0) scale = 1.0f / 32.0f;   // fold 1/sqrt(1024)
    int slice = r & 15, rtile = r >> 4;
    R = 1024; C = 64; rt = rtile * 64; ct = 0;
    soff = (size_t)slice * 65536;
    doff = (size_t)which * (1 << 20) + (size_t)slice * 65536;
  } else {
    src = Wp;
    R = 1024; C = 1024; rt = (r & 15) * 64; ct = (r >> 4) * 64;
    soff = 0; doff = (size_t)3 * (1 << 20);
  }
  const float* I = src + soff;
  u16* O = Wt + doff;
  const int t = threadIdx.x;
  const int c4 = (t & 15) * 4;
  #pragma unroll
  for (int i = 0; i < 4; i++) {
    int rr = i * 16 + (t >> 4);
    f32x4 v = *(const f32x4*)&I[(size_t)(rt + rr) * C + ct + c4];
    tile[rr][c4 + 0] = v[0]; tile[rr][c4 + 1] = v[1];
    tile[rr][c4 + 2] = v[2]; tile[rr][c4 + 3] = v[3];
  }
  __syncthreads();
  #pragma unroll
  for (int i = 0; i < 4; i++) {
    int oc = i * 16 + (t >> 4);
    u16x4 v;
    #pragma unroll
    for (int rr = 0; rr < 4; rr++) v[rr] = f2bf(tile[c4 + rr][oc] * scale);
    *(u16x4*)&O[(size_t)(ct + oc) * R + rt + c4] = v;
  }
}

// ---- prep: query/keys/values f32 -> bf16, one launch, grid 12288 ----
__global__ void k_convert3(const float* __restrict__ Xq, const float* __restrict__ Xk,
    const float* __restrict__ Xv, u16* __restrict__ dst) {
  const int bid = blockIdx.x;
  const int t = bid >> 12;                       // 0,1,2
  const float* X = t == 0 ? Xq : t == 1 ? Xk : Xv;
  u16* Y = dst + (size_t)t * (8 << 20);
  int i = ((bid & 4095) * 256 + threadIdx.x) * 8;
  float4 a = *(const float4*)(X + i);
  float4 b = *(const float4*)(X + i + 4);
  u16x8 v;
  v[0] = f2bf(a.x); v[1] = f2bf(a.y); v[2] = f2bf(a.z); v[3] = f2bf(a.w);
  v[4] = f2bf(b.x); v[5] = f2bf(b.y); v[6] = f2bf(b.z); v[7] = f2bf(b.w);
  *(u16x8*)(Y + i) = v;
}

#define STAGE_TILES() do { \
    GLL16(Ag + kt,             AsB0); \
    GLL16(Ag + 64 * 1024 + kt, AsB0 + 2048); \
    GLL16(Bg + kt,             BsB0); \
    GLL16(Bg + 64 * 1024 + kt, BsB0 + 2048); \
  } while (0)

#define READ_FRAGS() do { \
    _Pragma("unroll") \
    for (int mi = 0; mi < 4; mi++) \
      af[mi] = *(const u16x8*)&As[(wr * 64 + mi * 16 + lr) * 32 + lg * 8]; \
    _Pragma("unroll") \
    for (int ni = 0; ni < 4; ni++) \
      bf[ni] = *(const u16x8*)&Bs[(wc * 64 + ni * 16 + lr) * 32 + lg * 8]; \
  } while (0)

// ---- m97-structure GEMM: 128x128 tile, BK=32, 4 waves, global_load_lds staging ----
// MODE 0: merged QKV, grid (64,24). by 0..7 Q, 8..15 K (swapped mfma), 16..23 V (normal).
// MODE 2: C=AO@Wp' proj, grid (64,8) (swapped mfma -> f32x4 C+bias+residual into P)
template<int MODE>
__global__ __launch_bounds__(256) void k_gemm(
    const u16* __restrict__ X0, const u16* __restrict__ Ball,
    u16* __restrict__ O0, u16* __restrict__ O1, u16* __restrict__ O2,
    float* __restrict__ Pf, const float* __restrict__ bp,
    const float* __restrict__ query) {
  const int bid = blockIdx.x + (blockIdx.y << 6);
  const int bx  = ((bid & 7) << 3) + ((bid >> 3) & 7);   // m-tile, XCD-local slice
  const int by  = bid >> 6;                               // n-tile
  const int l  = threadIdx.x & 63;
  const int w  = threadIdx.x >> 6;
  const int lr = l & 15, lg = l >> 4;
  const int wr = w >> 1, wc = w & 1;
  const int m0 = bx * 128, n0 = by * 128;

  const u16* A = (MODE == 0) ? X0 + (size_t)(by >> 3) * (8 << 20) : X0;

  __shared__ __align__(16) u16 As[128 * 32];
  __shared__ __align__(16) u16 Bs[128 * 32];

  const int srow = w * 16 + (l >> 2);
  const int scol = (l & 3) * 8;
  const u16* Ag = A    + (size_t)(m0 + srow) * 1024 + scol;
  const u16* Bg = Ball + (size_t)(n0 + srow) * 1024 + scol;
  u16* AsB0 = As + w * 512;           // uniform per wave
  u16* BsB0 = Bs + w * 512;

  f32x4 acc[4][4] = {};
  u16x8 af[4], bf[4];

  if (MODE == 2 || by < 16) {
    for (int kt = 0; kt < 1024; kt += 32) {
      STAGE_TILES();
      __syncthreads();
      READ_FRAGS();
      #pragma unroll
      for (int mi = 0; mi < 4; mi++)
        #pragma unroll
        for (int ni = 0; ni < 4; ni++)
          acc[mi][ni] = MFMA16(bf[ni], af[mi], acc[mi][ni]);   // swapped
      __syncthreads();
    }
  } else {
    for (int kt = 0; kt < 1024; kt += 32) {
      STAGE_TILES();
      __syncthreads();
      READ_FRAGS();
      #pragma unroll
      for (int mi = 0; mi < 4; mi++)
        #pragma unroll
        for (int ni = 0; ni < 4; ni++)
          acc[mi][ni] = MFMA16(af[mi], bf[ni], acc[mi][ni]);   // normal (V)
      __syncthreads();
    }
  }

  if (MODE == 0 && by < 16) {
    u16* Out = (by >= 8) ? O1 : O0;
    const int h = (by & 7) * 2 + wc;
    #pragma unroll
    for (int mi = 0; mi < 4; mi++) {
      int s = m0 + wr * 64 + mi * 16 + lr;
      int bb = s >> 10, ss = s & 1023;
      #pragma unroll
      for (int ni = 0; ni < 4; ni++) {
        u16x4 v;
        #pragma unroll
        for (int r = 0; r < 4; r++) v[r] = f2bf(acc[mi][ni][r]);
        *(u16x4*)&Out[((size_t)(h * 8 + bb) * 1024 + ss) * 64 + ni * 16 + lg * 4] = v;
      }
    }
  } else if (MODE == 0) {
    const int byv = by - 16;
    const int h = byv * 2 + wc;
    #pragma unroll
    for (int mi = 0; mi < 4; mi++) {
      int s = m0 + wr * 64 + mi * 16 + lg * 4;
      int bb = s >> 10, ss = s & 1023;
      #pragma unroll
      for (int ni = 0; ni < 4; ni++) {
        u16x4 v;
        #pragma unroll
        for (int r = 0; r < 4; r++) v[r] = f2bf(acc[mi][ni][r]);
        *(u16x4*)&O2[((size_t)(h * 8 + bb) * 64 + ni * 16 + lr) * 1024 + ss] = v;
      }
    }
  } else {
    #pragma unroll
    for (int mi = 0; mi < 4; mi++) {
      int m = m0 + wr * 64 + mi * 16 + lr;
      #pragma unroll
      for (int ni = 0; ni < 4; ni++) {
        int n = n0 + wc * 64 + ni * 16 + lg * 4;
        f32x4 b4 = *(const f32x4*)(bp + n);
        f32x4 q4 = *(const f32x4*)(query + (size_t)m * 1024 + n);
        f32x4 o = acc[mi][ni] + b4 + q4;
        *(f32x4*)(Pf + (size_t)m * 1024 + n) = o;
      }
    }
  }
}

// ---- score kernel: QK^T + softmax + normalized attn f32 + normalized P bf16 ----
// wg = (hb, 16 q rows); 4 waves split k into 256-col slices; LDS = 512 B only.
__global__ __launch_bounds__(256, 4) void k_score(const u16* __restrict__ Qb,
    const u16* __restrict__ Kb, float* __restrict__ attn_out, u16* __restrict__ Pws) {
  const int bid = blockIdx.x;
  const int xcd = bid & 7, within = bid >> 3;
  const int qt = within & 63;
  const int hb = xcd * 16 + (within >> 6);
  const int w  = threadIdx.x >> 6;
  const int l  = threadIdx.x & 63;
  const int lr = l & 15, lg = l >> 4;
  const int q0 = qt * 16;

  __shared__ float wmaxs[4][16];
  __shared__ float wsums[4][16];

  // --- QK^T swapped: mfma(K,Q) -> thread holds S[q=lr][k = w*256 + j*16 + lg*4 + r]
  const u16* Qp = Qb + ((size_t)hb * 1024 + q0 + lr) * 64 + lg * 8;
  const u16* Kp = Kb + ((size_t)hb * 1024 + w * 256 + lr) * 64 + lg * 8;
  u16x8 q_lo = *(const u16x8*)Qp;
  u16x8 q_hi = *(const u16x8*)(Qp + 32);

  f32x4 sacc[16] = {};
  __builtin_amdgcn_s_setprio(1);
  #pragma unroll
  for (int j = 0; j < 16; j++) {
    u16x8 k0 = *(const u16x8*)(Kp + (size_t)j * 16 * 64);
    u16x8 k1 = *(const u16x8*)(Kp + (size_t)j * 16 * 64 + 32);
    sacc[j] = MFMA16(k0, q_lo, sacc[j]);
    sacc[j] = MFMA16(k1, q_hi, sacc[j]);
  }
  __builtin_amdgcn_s_setprio(0);

  // --- wave-local row max ---
  float mx = sacc[0][0];
  #pragma unroll
  for (int j = 0; j < 16; j++)
    #pragma unroll
    for (int r = 0; r < 4; r++) mx = fmaxf(mx, sacc[j][r]);
  mx = fmaxf(mx, __shfl_xor(mx, 16));
  mx = fmaxf(mx, __shfl_xor(mx, 32));

  // --- exp(s - wmax) + wave-local sum ---
  float sum = 0.f;
  #pragma unroll
  for (int j = 0; j < 16; j++)
    #pragma unroll
    for (int r = 0; r < 4; r++) {
      float p = __expf(sacc[j][r] - mx);
      sacc[j][r] = p;
      sum += p;
    }
  sum += __shfl_xor(sum, 16);
  sum += __shfl_xor(sum, 32);

  if (l < 16) { wmaxs[w][lr] = mx; wsums[w][lr] = sum; }
  __syncthreads();   // LDS-only drain (no global stores yet)

  // --- combine for row q = lr ---
  float m0v = wmaxs[0][lr], m1v = wmaxs[1][lr], m2v = wmaxs[2][lr], m3v = wmaxs[3][lr];
  float gmax = fmaxf(fmaxf(m0v, m1v), fmaxf(m2v, m3v));
  float gsum = wsums[0][lr] * __expf(m0v - gmax) + wsums[1][lr] * __expf(m1v - gmax)
             + wsums[2][lr] * __expf(m2v - gmax) + wsums[3][lr] * __expf(m3v - gmax);
  const float cown = __expf(mx - gmax) / gsum;   // own-slice normalizer

  // --- normalized attn f32 (nontemporal) + normalized P bf16 to ws ---
  float* Ap = attn_out + ((size_t)hb * 1024 + q0 + lr) * 1024 + w * 256 + lg * 4;
  u16*   Pp = Pws + ((size_t)hb * 1024 + q0 + lr) * 1024 + w * 256 + lg * 4;
  #pragma unroll
  for (int j = 0; j < 16; j++) {
    f32x4 v = sacc[j] * cown;
    __builtin_nontemporal_store(v, (f32x4*)(Ap + j * 16));
    u16x4 pb;
    #pragma unroll
    for (int r = 0; r < 4; r++) pb[r] = f2bf(v[r]);
    *(u16x4*)(Pp + j * 16) = pb;
  }
}

// ---- PV GEMM: AO[hb-part] = P[hb] @ V^T[hb]; BM=128(q) BN=64(e) BK=32 ----
// grid 1024: xcd=bid&7 owns hbs [xcd*16,+16); per hb 8 m-tiles.
__global__ __launch_bounds__(256) void k_pv(const u16* __restrict__ Pws,
    const u16* __restrict__ Vtb, u16* __restrict__ AO) {
  const int bid = blockIdx.x;
  const int xcd = bid & 7, within = bid >> 3;
  const int mt = within & 7;
  const int hb = xcd * 16 + (within >> 3);
  const int l  = threadIdx.x & 63;
  const int w  = threadIdx.x >> 6;
  const int lr = l & 15, lg = l >> 4;
  const int wr = w >> 1, wc = w & 1;
  const int m0 = mt * 128;

  __shared__ __align__(16) u16 As[128 * 32];   // P tile
  __shared__ __align__(16) u16 Bs[64 * 32];    // V^T tile

  const int srow = w * 16 + (l >> 2);
  const int scol = (l & 3) * 8;
  const u16* Ag = Pws + ((size_t)hb * 1024 + m0 + srow) * 1024 + scol;
  const u16* Bg = Vtb + ((size_t)hb * 64 + srow) * 1024 + scol;
  u16* AsB0 = As + w * 512;
  u16* BsB0 = Bs + w * 512;

  f32x4 acc[4][2] = {};

  for (int kt = 0; kt < 1024; kt += 32) {
    GLL16(Ag + kt,             AsB0);
    GLL16(Ag + 64 * 1024 + kt, AsB0 + 2048);
    GLL16(Bg + kt,             BsB0);
    __syncthreads();

    u16x8 af[4], bf[2];
    #pragma unroll
    for (int mi = 0; mi < 4; mi++)
      af[mi] = *(const u16x8*)&As[(wr * 64 + mi * 16 + lr) * 32 + lg * 8];
    #pragma unroll
    for (int ni = 0; ni < 2; ni++)
      bf[ni] = *(const u16x8*)&Bs[(wc * 32 + ni * 16 + lr) * 32 + lg * 8];

    #pragma unroll
    for (int mi = 0; mi < 4; mi++)
      #pragma unroll
      for (int ni = 0; ni < 2; ni++)
        acc[mi][ni] = MFMA16(bf[ni], af[mi], acc[mi][ni]);  // D[row=e][col=q]
    __syncthreads();
  }

  const int bb = hb & 7, hh = hb >> 3;
  #pragma unroll
  for (int mi = 0; mi < 4; mi++) {
    int q = m0 + wr * 64 + mi * 16 + lr;
    #pragma unroll
    for (int ni = 0; ni < 2; ni++) {
      int e = wc * 32 + ni * 16 + lg * 4;
      u16x4 v;
      #pragma unroll
      for (int r = 0; r < 4; r++) v[r] = f2bf(acc[mi][ni][r]);
      *(u16x4*)&AO[((size_t)bb * 1024 + q) * 1024 + hh * 64 + e] = v;
    }
  }
}

// ---- standalone LayerNorm over P rows (bias+residual already in P) ----
__global__ __launch_bounds__(256) void k_ln(const float* __restrict__ P,
    const float* __restrict__ gamma, const float* __restrict__ beta,
    float* __restrict__ y) {
  const int row = blockIdx.x * 4 + (threadIdx.x >> 6);
  const int l = threadIdx.x & 63;
  const float* p = P + (size_t)row * 1024 + l * 4;
  f32x4 v[4];
  float s = 0.f, s2 = 0.f;
  #pragma unroll
  for (int i = 0; i < 4; i++) {
    v[i] = *(const f32x4*)(p + i * 256);
    #pragma unroll
    for (int r = 0; r < 4; r++) { s += v[i][r]; s2 += v[i][r] * v[i][r]; }
  }
  #pragma unroll
  for (int off = 1; off < 64; off <<= 1) {
    s += __shfl_xor(s, off);
    s2 += __shfl_xor(s2, off);
  }
  float mu = s * (1.0f / 1024.0f);
  float var = s2 * (1.0f / 1024.0f) - mu * mu;
  float rstd = rsqrtf(var + LN_EPS);
  float* yp = y + (size_t)row * 1024 + l * 4;
  #pragma unroll
  for (int i = 0; i < 4; i++) {
    f32x4 g = *(const f32x4*)(gamma + l * 4 + i * 256);
    f32x4 b = *(const f32x4*)(beta + l * 4 + i * 256);
    f32x4 o;
    #pragma unroll
    for (int r = 0; r < 4; r++) o[r] = (v[i][r] - mu) * rstd * g[r] + b[r];
    __builtin_nontemporal_store(o, (f32x4*)(yp + i * 256));
  }
}

extern "C" void kernel_launch(void* const* d_in, const int* in_sizes, int n_in,
                              void* d_out, int out_size, void* d_ws, size_t ws_size,
                              hipStream_t stream) {
  const float* query  = (const float*)d_in[0];
  const float* keys   = (const float*)d_in[1];
  const float* values = (const float*)d_in[2];
  const float* Wq     = (const float*)d_in[3];
  const float* Wk     = (const float*)d_in[4];
  const float* Wv     = (const float*)d_in[5];
  const float* Wp     = (const float*)d_in[6];
  const float* bp     = (const float*)d_in[7];
  const float* gamma  = (const float*)d_in[8];
  const float* beta   = (const float*)d_in[9];

  float* y        = (float*)d_out;                         // [8,1024,1024]
  float* attn_out = (float*)d_out + (size_t)B_ * S_ * D_;  // [128,1024,1024]

  u16* ws  = (u16*)d_ws;
  u16* Wqt = ws;                   // weights: Wq|Wk|Wv|Wp transposed, 4M u16
  u16* Wpt = Wqt + (3 << 20);
  u16* Xqb = Wqt + (4 << 20);      // Xq|Xk|Xv bf16, 24M u16
  u16* Qb  = Xqb + (24 << 20);     // 8M each
  u16* Kb  = Qb + (8 << 20);
  u16* Vtb = Kb + (8 << 20);
  u16* AO  = Vtb + (8 << 20);      // 8M
  u16* Pws = AO + (8 << 20);       // 8M  (normalized softmax bf16)
  float* P = (float*)Xqb;          // proj+residual f32, overlays Xqb/Xkb (dead by then)

  k_transpose_all<<<1024, 256, 0, stream>>>(Wq, Wk, Wv, Wp, Wqt);
  k_convert3<<<12288, 256, 0, stream>>>(query, keys, values, Xqb);

  // merged QKV GEMM: by 0..7 Q, 8..15 K, 16..23 V
  k_gemm<0><<<dim3(64, 24), 256, 0, stream>>>(Xqb, Wqt, Qb, Kb, Vtb, nullptr, nullptr, nullptr);

  k_score<<<8192, 256, 0, stream>>>(Qb, Kb, attn_out, Pws);
  k_pv<<<1024, 256, 0, stream>>>(Pws, Vtb, AO);

  k_gemm<2><<<dim3(64, 8), 256, 0, stream>>>(AO, Wpt, nullptr, nullptr, nullptr, P, bp, query);
  k_ln<<<2048, 256, 0, stream>>>(P, gamma, beta, y);
}

// Round 8
// 413.581 us; speedup vs baseline: 1.2106x; 1.2106x over previous
//
#include <hip/hip_runtime.h>
#include <hip/hip_bf16.h>

#define H_ 16
#define B_ 8
#define S_ 1024
#define D_ 1024
#define E_ 64
#define HB_ 128
#define LN_EPS 1e-5f
#define LOG2E 1.4426950408889634f

typedef unsigned short u16;
typedef __bf16 bf16x8 __attribute__((ext_vector_type(8)));
typedef u16 u16x8 __attribute__((ext_vector_type(8)));
typedef u16 u16x4 __attribute__((ext_vector_type(4)));
typedef float f32x4 __attribute__((ext_vector_type(4)));

#define MFMA16(a, b, c) __builtin_amdgcn_mfma_f32_16x16x32_bf16( \
    __builtin_bit_cast(bf16x8, (a)), __builtin_bit_cast(bf16x8, (b)), (c), 0, 0, 0)

// async global->LDS, 16B per lane; LDS dest must be wave-uniform base (+lane*16 by HW)
#define GLL16(gp, lp) __builtin_amdgcn_global_load_lds( \
    (const __attribute__((address_space(1))) void*)(gp), \
    (__attribute__((address_space(3))) void*)(lp), 16, 0, 0)

__device__ __forceinline__ u16 f2bf(float x) {
  union { float f; unsigned u; } v; v.f = x;
  unsigned r = v.u + 0x7fffu + ((v.u >> 16) & 1u);
  return (u16)(r >> 16);
}

// packed f32x2 -> bf16x2 (RNE), 1 instr for 2 values
__device__ __forceinline__ unsigned cvt_pk_bf16(float lo, float hi) {
  unsigned r;
  asm("v_cvt_pk_bf16_f32 %0, %1, %2" : "=v"(r) : "v"(lo), "v"(hi));
  return r;
}
__device__ __forceinline__ u16x4 pk4(f32x4 v) {
  union { unsigned u[2]; u16x4 s; } r;
  r.u[0] = cvt_pk_bf16(v[0], v[1]);
  r.u[1] = cvt_pk_bf16(v[2], v[3]);
  return r.s;
}
// raw v_exp_f32: computes 2^x
__device__ __forceinline__ float exp2_hw(float x) {
  float r;
  asm("v_exp_f32 %0, %1" : "=v"(r) : "v"(x));
  return r;
}

// ---- prep: all weight transposes in one launch. flat grid 1024 wgs.
// Wq folded scale = log2(e)/sqrt(1024): scores come out in exp2 domain.
__global__ __launch_bounds__(256) void k_transpose_all(
    const float* __restrict__ Wq, const float* __restrict__ Wk,
    const float* __restrict__ Wv, const float* __restrict__ Wp,
    u16* __restrict__ Wt) {
  __shared__ float tile[64][65];
  const int bid = blockIdx.x;
  const int which = bid >> 8, r = bid & 255;
  const float* src;
  int R, C, rt, ct;
  float scale = 1.0f;
  size_t soff, doff;
  if (which < 3) {
    src = which == 0 ? Wq : which == 1 ? Wk : Wv;
    if (which == 0) scale = LOG2E / 32.0f;
    int slice = r & 15, rtile = r >> 4;
    R = 1024; C = 64; rt = rtile * 64; ct = 0;
    soff = (size_t)slice * 65536;
    doff = (size_t)which * (1 << 20) + (size_t)slice * 65536;
  } else {
    src = Wp;
    R = 1024; C = 1024; rt = (r & 15) * 64; ct = (r >> 4) * 64;
    soff = 0; doff = (size_t)3 * (1 << 20);
  }
  const float* I = src + soff;
  u16* O = Wt + doff;
  const int t = threadIdx.x;
  const int c4 = (t & 15) * 4;
  #pragma unroll
  for (int i = 0; i < 4; i++) {
    int rr = i * 16 + (t >> 4);
    f32x4 v = *(const f32x4*)&I[(size_t)(rt + rr) * C + ct + c4];
    tile[rr][c4 + 0] = v[0]; tile[rr][c4 + 1] = v[1];
    tile[rr][c4 + 2] = v[2]; tile[rr][c4 + 3] = v[3];
  }
  __syncthreads();
  #pragma unroll
  for (int i = 0; i < 4; i++) {
    int oc = i * 16 + (t >> 4);
    f32x4 tv;
    #pragma unroll
    for (int rr = 0; rr < 4; rr++) tv[rr] = tile[c4 + rr][oc] * scale;
    *(u16x4*)&O[(size_t)(ct + oc) * R + rt + c4] = pk4(tv);
  }
}

// ---- prep: query/keys/values f32 -> bf16, one launch, grid 12288 ----
__global__ void k_convert3(const float* __restrict__ Xq, const float* __restrict__ Xk,
    const float* __restrict__ Xv, u16* __restrict__ dst) {
  const int bid = blockIdx.x;
  const int t = bid >> 12;                       // 0,1,2
  const float* X = t == 0 ? Xq : t == 1 ? Xk : Xv;
  u16* Y = dst + (size_t)t * (8 << 20);
  int i = ((bid & 4095) * 256 + threadIdx.x) * 8;
  f32x4 a = *(const f32x4*)(X + i);
  f32x4 b = *(const f32x4*)(X + i + 4);
  union { unsigned u[4]; u16x8 s; } v;
  v.u[0] = cvt_pk_bf16(a[0], a[1]);
  v.u[1] = cvt_pk_bf16(a[2], a[3]);
  v.u[2] = cvt_pk_bf16(b[0], b[1]);
  v.u[3] = cvt_pk_bf16(b[2], b[3]);
  *(u16x8*)(Y + i) = v.s;
}

#define STAGE_TILES() do { \
    GLL16(Ag + kt,             AsB0); \
    GLL16(Ag + 64 * 1024 + kt, AsB0 + 2048); \
    GLL16(Bg + kt,             BsB0); \
    GLL16(Bg + 64 * 1024 + kt, BsB0 + 2048); \
  } while (0)

#define READ_FRAGS() do { \
    _Pragma("unroll") \
    for (int mi = 0; mi < 4; mi++) \
      af[mi] = *(const u16x8*)&As[(wr * 64 + mi * 16 + lr) * 32 + lg * 8]; \
    _Pragma("unroll") \
    for (int ni = 0; ni < 4; ni++) \
      bf[ni] = *(const u16x8*)&Bs[(wc * 64 + ni * 16 + lr) * 32 + lg * 8]; \
  } while (0)

// ---- m97-structure GEMM: 128x128 tile, BK=32, 4 waves, global_load_lds staging ----
// MODE 0: merged QKV, grid (64,24). by 0..7 Q, 8..15 K (swapped mfma), 16..23 V (normal).
// MODE 2: C=AO@Wp' proj, grid (64,8) (swapped mfma -> f32x4 C+bias+residual into P)
template<int MODE>
__global__ __launch_bounds__(256) void k_gemm(
    const u16* __restrict__ X0, const u16* __restrict__ Ball,
    u16* __restrict__ O0, u16* __restrict__ O1, u16* __restrict__ O2,
    float* __restrict__ Pf, const float* __restrict__ bp,
    const float* __restrict__ query) {
  const int bid = blockIdx.x + (blockIdx.y << 6);
  const int bx  = ((bid & 7) << 3) + ((bid >> 3) & 7);   // m-tile, XCD-local slice
  const int by  = bid >> 6;                               // n-tile
  const int l  = threadIdx.x & 63;
  const int w  = threadIdx.x >> 6;
  const int lr = l & 15, lg = l >> 4;
  const int wr = w >> 1, wc = w & 1;
  const int m0 = bx * 128, n0 = by * 128;

  const u16* A = (MODE == 0) ? X0 + (size_t)(by >> 3) * (8 << 20) : X0;

  __shared__ __align__(16) u16 As[128 * 32];
  __shared__ __align__(16) u16 Bs[128 * 32];

  const int srow = w * 16 + (l >> 2);
  const int scol = (l & 3) * 8;
  const u16* Ag = A    + (size_t)(m0 + srow) * 1024 + scol;
  const u16* Bg = Ball + (size_t)(n0 + srow) * 1024 + scol;
  u16* AsB0 = As + w * 512;           // uniform per wave
  u16* BsB0 = Bs + w * 512;

  f32x4 acc[4][4] = {};
  u16x8 af[4], bf[4];

  if (MODE == 2 || by < 16) {
    for (int kt = 0; kt < 1024; kt += 32) {
      STAGE_TILES();
      __syncthreads();
      READ_FRAGS();
      #pragma unroll
      for (int mi = 0; mi < 4; mi++)
        #pragma unroll
        for (int ni = 0; ni < 4; ni++)
          acc[mi][ni] = MFMA16(bf[ni], af[mi], acc[mi][ni]);   // swapped
      __syncthreads();
    }
  } else {
    for (int kt = 0; kt < 1024; kt += 32) {
      STAGE_TILES();
      __syncthreads();
      READ_FRAGS();
      #pragma unroll
      for (int mi = 0; mi < 4; mi++)
        #pragma unroll
        for (int ni = 0; ni < 4; ni++)
          acc[mi][ni] = MFMA16(af[mi], bf[ni], acc[mi][ni]);   // normal (V)
      __syncthreads();
    }
  }

  if (MODE == 0 && by < 16) {
    u16* Out = (by >= 8) ? O1 : O0;
    const int h = (by & 7) * 2 + wc;
    #pragma unroll
    for (int mi = 0; mi < 4; mi++) {
      int s = m0 + wr * 64 + mi * 16 + lr;
      int bb = s >> 10, ss = s & 1023;
      #pragma unroll
      for (int ni = 0; ni < 4; ni++)
        *(u16x4*)&Out[((size_t)(h * 8 + bb) * 1024 + ss) * 64 + ni * 16 + lg * 4] =
            pk4(acc[mi][ni]);
    }
  } else if (MODE == 0) {
    const int byv = by - 16;
    const int h = byv * 2 + wc;
    #pragma unroll
    for (int mi = 0; mi < 4; mi++) {
      int s = m0 + wr * 64 + mi * 16 + lg * 4;
      int bb = s >> 10, ss = s & 1023;
      #pragma unroll
      for (int ni = 0; ni < 4; ni++)
        *(u16x4*)&O2[((size_t)(h * 8 + bb) * 64 + ni * 16 + lr) * 1024 + ss] =
            pk4(acc[mi][ni]);
    }
  } else {
    #pragma unroll
    for (int mi = 0; mi < 4; mi++) {
      int m = m0 + wr * 64 + mi * 16 + lr;
      #pragma unroll
      for (int ni = 0; ni < 4; ni++) {
        int n = n0 + wc * 64 + ni * 16 + lg * 4;
        f32x4 b4 = *(const f32x4*)(bp + n);
        f32x4 q4 = *(const f32x4*)(query + (size_t)m * 1024 + n);
        f32x4 o = acc[mi][ni] + b4 + q4;
        *(f32x4*)(Pf + (size_t)m * 1024 + n) = o;
      }
    }
  }
}

// ---- attention: wg = (hb, 16 q rows); ONE barrier; all global stores after it ----
// Scores arrive in exp2 domain (log2e folded into Wq). flat grid 8192, XCD-swizzled.
__global__ __launch_bounds__(256, 4) void k_attn(const u16* __restrict__ Qb,
    const u16* __restrict__ Kb, const u16* __restrict__ Vtb,
    float* __restrict__ attn_out, u16* __restrict__ AO) {
  const int bid = blockIdx.x;
  const int xcd = bid & 7, within = bid >> 3;
  const int qt = within & 63;
  const int hb = xcd * 16 + (within >> 6);
  const int w  = threadIdx.x >> 6;
  const int l  = threadIdx.x & 63;
  const int lr = l & 15, lg = l >> 4;
  const int q0 = qt * 16;

  __shared__ __align__(16) u16 pbuf[16 * 1024];   // 32 KB, swizzled; raw exp2(s - wmax_w)
  __shared__ float wmaxs[4][16];
  __shared__ float wsums[4][16];

  // --- QK^T swapped: mfma(K,Q) -> thread holds S[q=lr][k = w*256 + j*16 + lg*4 + r]
  const u16* Qp = Qb + ((size_t)hb * 1024 + q0 + lr) * 64 + lg * 8;
  const u16* Kp = Kb + ((size_t)hb * 1024 + w * 256 + lr) * 64 + lg * 8;
  u16x8 q_lo = *(const u16x8*)Qp;
  u16x8 q_hi = *(const u16x8*)(Qp + 32);

  f32x4 sacc[16] = {};
  __builtin_amdgcn_s_setprio(1);
  #pragma unroll
  for (int j = 0; j < 16; j++) {
    u16x8 k0 = *(const u16x8*)(Kp + (size_t)j * 16 * 64);
    u16x8 k1 = *(const u16x8*)(Kp + (size_t)j * 16 * 64 + 32);
    sacc[j] = MFMA16(k0, q_lo, sacc[j]);
    sacc[j] = MFMA16(k1, q_hi, sacc[j]);
  }
  __builtin_amdgcn_s_setprio(0);

  // --- wave-local row max over this wave's 256-col slice ---
  float mx = sacc[0][0];
  #pragma unroll
  for (int j = 0; j < 16; j++)
    #pragma unroll
    for (int r = 0; r < 4; r++) mx = fmaxf(mx, sacc[j][r]);
  mx = fmaxf(mx, __shfl_xor(mx, 16));
  mx = fmaxf(mx, __shfl_xor(mx, 32));

  // --- exp2(s - wmax) + wave-local sum (v_exp_f32 is 2^x; scores pre-scaled) ---
  float sum = 0.f;
  #pragma unroll
  for (int j = 0; j < 16; j++)
    #pragma unroll
    for (int r = 0; r < 4; r++) {
      float p = exp2_hw(sacc[j][r] - mx);
      sacc[j][r] = p;
      sum += p;
    }
  sum += __shfl_xor(sum, 16);
  sum += __shfl_xor(sum, 32);

  // --- prefetch first 4 V fragments (latency hides under LDS writes + barrier) ---
  const u16* Vp = Vtb + ((size_t)hb * 64 + w * 16 + lr) * 1024 + lg * 8;
  u16x8 vp0 = *(const u16x8*)(Vp + 0);
  u16x8 vp1 = *(const u16x8*)(Vp + 32);
  u16x8 vp2 = *(const u16x8*)(Vp + 64);
  u16x8 vp3 = *(const u16x8*)(Vp + 96);

  // --- raw-exp2 P -> swizzled pbuf (bf16), before the barrier ---
  #pragma unroll
  for (int j = 0; j < 16; j++) {
    int k0 = w * 256 + j * 16 + lg * 4;
    int byte = (lr * 2048 + k0 * 2) ^ ((lr & 7) << 4);
    *(u16x4*)((char*)pbuf + byte) = pk4(sacc[j]);
  }
  if (l < 16) { wmaxs[w][lr] = mx; wsums[w][lr] = sum; }

  __syncthreads();   // the only barrier: drains LDS writes only (no global stores yet)

  // --- combine: gmax, gsum, per-slice coefficients (all for row q = lr) ---
  float m0v = wmaxs[0][lr], m1v = wmaxs[1][lr], m2v = wmaxs[2][lr], m3v = wmaxs[3][lr];
  float gmax = fmaxf(fmaxf(m0v, m1v), fmaxf(m2v, m3v));
  float e0 = exp2_hw(m0v - gmax), e1 = exp2_hw(m1v - gmax);
  float e2 = exp2_hw(m2v - gmax), e3 = exp2_hw(m3v - gmax);
  float gsum = wsums[0][lr] * e0 + wsums[1][lr] * e1 + wsums[2][lr] * e2 + wsums[3][lr] * e3;
  float inv = 1.0f / gsum;
  float c0 = e0 * inv, c1 = e1 * inv, c2 = e2 * inv, c3 = e3 * inv;
  float scale_own = exp2_hw(mx - gmax) * inv;   // == c_w for own wave

  // --- normalized attn f32 out (nontemporal; overlaps PV below) ---
  float* Ap = attn_out + ((size_t)hb * 1024 + q0 + lr) * 1024 + w * 256 + lg * 4;
  #pragma unroll
  for (int j = 0; j < 16; j++) {
    f32x4 v = sacc[j] * scale_own;
    __builtin_nontemporal_store(v, (f32x4*)(Ap + j * 16));
  }

  // --- PV with swapped operands: mfma(V, P) -> D[row=e][col=q=lr]
  //     per-k-slice partials, combined with per-slice coefs afterwards ---
  f32x4 o0 = {}, o1 = {}, o2 = {}, o3 = {};
  __builtin_amdgcn_s_setprio(1);
  #pragma unroll
  for (int i = 0; i < 4; i++)
    #pragma unroll
    for (int kk = 0; kk < 8; kk++) {
      int kb = i * 256 + kk * 32 + lg * 8;
      int byte = (lr * 2048 + kb * 2) ^ ((lr & 7) << 4);
      u16x8 p = *(u16x8*)((char*)pbuf + byte);
      u16x8 v;
      if (i == 0 && kk == 0) v = vp0;
      else if (i == 0 && kk == 1) v = vp1;
      else if (i == 0 && kk == 2) v = vp2;
      else if (i == 0 && kk == 3) v = vp3;
      else v = *(const u16x8*)(Vp + i * 256 + kk * 32);
      if (i == 0) o0 = MFMA16(v, p, o0);
      else if (i == 1) o1 = MFMA16(v, p, o1);
      else if (i == 2) o2 = MFMA16(v, p, o2);
      else o3 = MFMA16(v, p, o3);
    }
  __builtin_amdgcn_s_setprio(0);

  // --- combine + AO store: q = lr, e = w*16 + lg*4 + r -> one u16x4 ---
  const int bb = hb & 7, hh = hb >> 3;
  f32x4 oc;
  #pragma unroll
  for (int r = 0; r < 4; r++)
    oc[r] = o0[r] * c0 + o1[r] * c1 + o2[r] * c2 + o3[r] * c3;
  *(u16x4*)&AO[((size_t)bb * 1024 + q0 + lr) * 1024 + hh * 64 + w * 16 + lg * 4] = pk4(oc);
}

// ---- standalone LayerNorm over P rows (bias+residual already in P) ----
__global__ __launch_bounds__(256) void k_ln(const float* __restrict__ P,
    const float* __restrict__ gamma, const float* __restrict__ beta,
    float* __restrict__ y) {
  const int row = blockIdx.x * 4 + (threadIdx.x >> 6);
  const int l = threadIdx.x & 63;
  const float* p = P + (size_t)row * 1024 + l * 4;
  f32x4 v[4];
  float s = 0.f, s2 = 0.f;
  #pragma unroll
  for (int i = 0; i < 4; i++) {
    v[i] = *(const f32x4*)(p + i * 256);
    #pragma unroll
    for (int r = 0; r < 4; r++) { s += v[i][r]; s2 += v[i][r] * v[i][r]; }
  }
  #pragma unroll
  for (int off = 1; off < 64; off <<= 1) {
    s += __shfl_xor(s, off);
    s2 += __shfl_xor(s2, off);
  }
  float mu = s * (1.0f / 1024.0f);
  float var = s2 * (1.0f / 1024.0f) - mu * mu;
  float rstd = rsqrtf(var + LN_EPS);
  float* yp = y + (size_t)row * 1024 + l * 4;
  #pragma unroll
  for (int i = 0; i < 4; i++) {
    f32x4 g = *(const f32x4*)(gamma + l * 4 + i * 256);
    f32x4 b = *(const f32x4*)(beta + l * 4 + i * 256);
    f32x4 o;
    #pragma unroll
    for (int r = 0; r < 4; r++) o[r] = (v[i][r] - mu) * rstd * g[r] + b[r];
    __builtin_nontemporal_store(o, (f32x4*)(yp + i * 256));
  }
}

extern "C" void kernel_launch(void* const* d_in, const int* in_sizes, int n_in,
                              void* d_out, int out_size, void* d_ws, size_t ws_size,
                              hipStream_t stream) {
  const float* query  = (const float*)d_in[0];
  const float* keys   = (const float*)d_in[1];
  const float* values = (const float*)d_in[2];
  const float* Wq     = (const float*)d_in[3];
  const float* Wk     = (const float*)d_in[4];
  const float* Wv     = (const float*)d_in[5];
  const float* Wp     = (const float*)d_in[6];
  const float* bp     = (const float*)d_in[7];
  const float* gamma  = (const float*)d_in[8];
  const float* beta   = (const float*)d_in[9];

  float* y        = (float*)d_out;                         // [8,1024,1024]
  float* attn_out = (float*)d_out + (size_t)B_ * S_ * D_;  // [128,1024,1024]

  u16* ws  = (u16*)d_ws;
  u16* Wqt = ws;                   // weights: Wq|Wk|Wv|Wp transposed, 4M u16
  u16* Wpt = Wqt + (3 << 20);
  u16* Xqb = Wqt + (4 << 20);      // Xq|Xk|Xv bf16, 24M u16
  u16* Qb  = Xqb + (24 << 20);     // 8M each
  u16* Kb  = Qb + (8 << 20);
  u16* Vtb = Kb + (8 << 20);
  u16* AO  = Vtb + (8 << 20);      // 8M
  float* P = (float*)Xqb;          // proj+residual f32, overlays Xqb/Xkb (dead by then)

  k_transpose_all<<<1024, 256, 0, stream>>>(Wq, Wk, Wv, Wp, Wqt);
  k_convert3<<<12288, 256, 0, stream>>>(query, keys, values, Xqb);

  // merged QKV GEMM: by 0..7 Q, 8..15 K, 16..23 V
  k_gemm<0><<<dim3(64, 24), 256, 0, stream>>>(Xqb, Wqt, Qb, Kb, Vtb, nullptr, nullptr, nullptr);

  k_attn<<<8192, 256, 0, stream>>>(Qb, Kb, Vtb, attn_out, AO);

  k_gemm<2><<<dim3(64, 8), 256, 0, stream>>>(AO, Wpt, nullptr, nullptr, nullptr, P, bp, query);
  k_ln<<<2048, 256, 0, stream>>>(P, gamma, beta, y);
}